// Round 11
// baseline (307.046 us; speedup 1.0000x reference)
//
#include <hip/hip_runtime.h>

#define HID 128
#define ELLW 64

// ---- binned ELL build params ----
#define NBINS 400          // buckets of 256 dst nodes; supports N <= 102400
#define BINCAP 38          // LDS bin capacity
#define CHUNK_I4 1024      // 4096 edges per block in pass A
#define BKCAP 5120         // global bucket capacity
#define OVF_CAP 16384

typedef _Float16 half8 __attribute__((ext_vector_type(8)));
typedef float f32x4 __attribute__((ext_vector_type(4)));
struct alignas(8) H4v { _Float16 x, y, z, w; };

// ---------------- pass A: bin edges by dst>>8 with LDS staging ----------------

__global__ void k_zero_ints(int* p, int n) {
  int i = blockIdx.x * blockDim.x + threadIdx.x;
  if (i < n) p[i] = 0;
}

__device__ __forceinline__ void bin_one(int s, int d, int* lcnt, unsigned* bins,
                                        int* ovfn, int2* ovf) {
  int b = d >> 8;
  int p = atomicAdd(&lcnt[b], 1);
  if (p < BINCAP) bins[b * BINCAP + p] = ((unsigned)s << 8) | (unsigned)(d & 255);
  else { int q = atomicAdd(ovfn, 1); if (q < OVF_CAP) ovf[q] = make_int2(s, d); }
}

__global__ __launch_bounds__(256) void k_binA(
    const int4* __restrict__ src4, const int4* __restrict__ dst4, int E4,
    int* bkcnt, unsigned* __restrict__ bk, int* ovfn, int2* __restrict__ ovf) {
  __shared__ unsigned bins[NBINS * BINCAP];
  __shared__ int lcnt[NBINS];
  __shared__ int gbase[NBINS];
  int t = threadIdx.x;
  for (int b = t; b < NBINS; b += 256) lcnt[b] = 0;
  __syncthreads();

  int i0 = blockIdx.x * CHUNK_I4;
  int i1 = min(i0 + CHUNK_I4, E4);
  for (int i = i0 + t; i < i1; i += 256) {
    int4 d = dst4[i];
    int4 s = src4[i];
    bin_one(s.x, d.x, lcnt, bins, ovfn, ovf);
    bin_one(s.y, d.y, lcnt, bins, ovfn, ovf);
    bin_one(s.z, d.z, lcnt, bins, ovfn, ovf);
    bin_one(s.w, d.w, lcnt, bins, ovfn, ovf);
  }
  __syncthreads();

  for (int b = t; b < NBINS; b += 256) gbase[b] = atomicAdd(&bkcnt[b], min(lcnt[b], BINCAP));
  __syncthreads();

  int wid = t >> 6, lane = t & 63;
  for (int b = wid; b < NBINS; b += 4) {
    int c = min(lcnt[b], BINCAP);
    if (lane < c) {
      int off = gbase[b] + lane;
      unsigned r = bins[b * BINCAP + lane];
      if (off < BKCAP) bk[(size_t)b * BKCAP + off] = r;
      else {
        int q = atomicAdd(ovfn, 1);
        if (q < OVF_CAP) ovf[q] = make_int2((int)(r >> 8), b * 256 + (int)(r & 255));
      }
    }
  }
}

__global__ void k_tail_ovf(const int* __restrict__ src, const int* __restrict__ dst,
                           int e0, int E, int* ovfn, int2* __restrict__ ovf) {
  int e = e0 + threadIdx.x;
  if (e < E) {
    int q = atomicAdd(ovfn, 1);
    if (q < OVF_CAP) ovf[q] = make_int2(src[e], dst[e]);
  }
}

// ---------------- pass B: per-bucket ELL build ----------------

__global__ __launch_bounds__(256) void k_ell_build2(
    const unsigned* __restrict__ bk, const int* __restrict__ bkcnt,
    int* __restrict__ ell, int* __restrict__ cnt, int N) {
  int b = blockIdx.x;
  int t = threadIdx.x;
  __shared__ int lcnt[256];
  lcnt[t] = 0;
  __syncthreads();
  int n = bkcnt[b]; if (n > BKCAP) n = BKCAP;
  const unsigned* my = bk + (size_t)b * BKCAP;
  for (int k = t; k < n; k += 256) {
    unsigned r = my[k];
    int d0 = (int)(r & 255);
    int s = (int)(r >> 8);
    int p = atomicAdd(&lcnt[d0], 1);
    if (p < ELLW) ell[(size_t)(b * 256 + d0) * ELLW + p] = s;
  }
  __syncthreads();
  int node = b * 256 + t;
  if (node < N) cnt[node] = lcnt[t];
}

__global__ void k_ovf_build(const int2* __restrict__ ovf, const int* __restrict__ ovfn,
                            int* cnt, int* ell) {
  int n = *ovfn; if (n > OVF_CAP) n = OVF_CAP;
  for (int k = threadIdx.x; k < n; k += blockDim.x) {
    int2 e = ovf[k];
    int p = atomicAdd(&cnt[e.y], 1);
    if (p < ELLW) ell[(size_t)e.y * ELLW + p] = e.x;
  }
}

__global__ void k_fill_ell1(const int* __restrict__ src, const int* __restrict__ dst,
                            int* cnt, int* ell, int E) {
  int e = blockIdx.x * blockDim.x + threadIdx.x;
  if (e < E) {
    int d = dst[e];
    int p = atomicAdd(&cnt[d], 1);
    if (p < ELLW) ell[(size_t)d * ELLW + p] = src[e];
  }
}

// ---------------- dis + prep_x fused ----------------

__global__ void k_dis_prepx(const int* __restrict__ cnt, const float* __restrict__ x,
                            float* __restrict__ dis, float4* __restrict__ x4, int N) {
  int i = blockIdx.x * blockDim.x + threadIdx.x;
  if (i >= N) return;
  float s = rsqrtf((float)(cnt[i] + 1));
  dis[i] = s;
  x4[i] = make_float4(s * x[i * 3 + 0], s * x[i * 3 + 1], s * x[i * 3 + 2], 0.f);
}

// ---------------- layer 0 aggregate (unrolled x4) ----------------

__global__ void k_agg3(const float4* __restrict__ x4, const int* __restrict__ ell,
                       const int* __restrict__ cnt, const float* __restrict__ dis,
                       float4* __restrict__ z4, int N) {
  int i = blockIdx.x * blockDim.x + threadIdx.x;
  if (i >= N) return;
  float4 a = x4[i];
  int c = cnt[i]; if (c > ELLW) c = ELLW;
  const int* row = &ell[(size_t)i * ELLW];
  int k = 0;
  for (; k + 4 <= c; k += 4) {
    int4 s4 = *(const int4*)(row + k);
    float4 v0 = x4[s4.x], v1 = x4[s4.y], v2 = x4[s4.z], v3 = x4[s4.w];
    a.x += (v0.x + v1.x) + (v2.x + v3.x);
    a.y += (v0.y + v1.y) + (v2.y + v3.y);
    a.z += (v0.z + v1.z) + (v2.z + v3.z);
  }
  for (; k < c; ++k) {
    float4 v = x4[row[k]];
    a.x += v.x; a.y += v.y; a.z += v.z;
  }
  float s = dis[i];
  z4[i] = make_float4(s * a.x, s * a.y, s * a.z, 0.f);
}

// ---------------- both weights -> fp16 transposed [n][k] ----------------

__global__ void k_prep_w16x2(const float* __restrict__ W1, const float* __restrict__ W2,
                             _Float16* __restrict__ Wt1, _Float16* __restrict__ Wt2) {
  int idx = blockIdx.x * blockDim.x + threadIdx.x;
  if (idx >= 2 * HID * HID) return;
  int which = idx >> 14;
  int r = idx & (HID * HID - 1);
  int k = r >> 7, n = r & 127;
  const float* W = which ? W2 : W1;
  _Float16* Wt = which ? Wt2 : Wt1;
  Wt[n * HID + k] = (_Float16)W[r];
}

// ---------------- fused layer0-transform + layer1-GEMM ----------------

__global__ __launch_bounds__(256) void k_l01(
    const float4* __restrict__ z4, const float* __restrict__ W0,
    const float* __restrict__ b0, const _Float16* __restrict__ wt1,
    const float* __restrict__ dis, _Float16* __restrict__ G, int N) {
  __shared__ _Float16 hs[64][136];
  int t = threadIdx.x;
  int base = blockIdx.x * 64;

  {
    int r = t >> 2;
    int c0 = (t & 3) * 32;
    int row = base + r;
    float4 z = make_float4(0.f, 0.f, 0.f, 0.f);
    if (row < N) z = z4[row];
#pragma unroll
    for (int c = 0; c < 32; c += 4) {
      int cc = c0 + c;
      float4 w0 = *(const float4*)&W0[0 * HID + cc];
      float4 w1 = *(const float4*)&W0[1 * HID + cc];
      float4 w2 = *(const float4*)&W0[2 * HID + cc];
      float4 bb = *(const float4*)&b0[cc];
      H4v o;
      o.x = (_Float16)fmaxf(z.x * w0.x + z.y * w1.x + z.z * w2.x + bb.x, 0.f);
      o.y = (_Float16)fmaxf(z.x * w0.y + z.y * w1.y + z.z * w2.y + bb.y, 0.f);
      o.z = (_Float16)fmaxf(z.x * w0.z + z.y * w1.z + z.z * w2.z + bb.z, 0.f);
      o.w = (_Float16)fmaxf(z.x * w0.w + z.y * w1.w + z.z * w2.w + bb.w, 0.f);
      *(H4v*)&hs[r][cc] = o;
    }
  }
  __syncthreads();

  int w = t >> 6, lane = t & 63;
  int kg = lane >> 4, ccol = lane & 15;
  int lrow = w * 16 + ccol;

  f32x4 acc[8];
#pragma unroll
  for (int nt = 0; nt < 8; ++nt) acc[nt] = (f32x4){0.f, 0.f, 0.f, 0.f};

#pragma unroll
  for (int kt = 0; kt < 4; ++kt) {
    half8 a = *(const half8*)&hs[lrow][kg * 8 + kt * 32];
#pragma unroll
    for (int nt = 0; nt < 8; ++nt) {
      half8 b = *(const half8*)(wt1 + (size_t)(nt * 16 + ccol) * HID + kg * 8 + kt * 32);
      acc[nt] = __builtin_amdgcn_mfma_f32_16x16x32_f16(a, b, acc[nt], 0, 0, 0);
    }
  }

#pragma unroll
  for (int j = 0; j < 4; ++j) {
    int row = base + w * 16 + kg * 4 + j;
    if (row < N) {
      float s = dis[row];
#pragma unroll
      for (int nt = 0; nt < 8; ++nt) {
        G[(size_t)row * HID + nt * 16 + ccol] = (_Float16)(s * acc[nt][j]);
      }
    }
  }
}

// ---------------- fused gather + layer2-GEMM, barrier-free (A-frag-direct) ----------
// wave w owns rows [blk*64 + w*16, +16). lane = (row = lane&15, kg = lane>>4).
// lane gathers row's cols {kg*8 + kt*32 + j} (4x half8 per edge) into registers,
// applies relu(dis*. + b1) -> A-frags, then the wave MFMAs its own 16x128 tile.

__global__ __launch_bounds__(256) void k_gg2(
    const _Float16* __restrict__ Gin, const int* __restrict__ ell,
    const int* __restrict__ cnt, const float* __restrict__ dis,
    const float* __restrict__ b1, const _Float16* __restrict__ wt2,
    _Float16* __restrict__ Gout, int N) {
  int t = threadIdx.x;
  int w = t >> 6, lane = t & 63;
  int kg = lane >> 4;            // 0..3
  int rloc = lane & 15;          // row within tile
  int m0 = blockIdx.x * 64 + w * 16;
  int row = m0 + rloc;
  int rclamp = (row < N) ? row : (N - 1);

  // ---- gather phase ----
  float acc[4][8];
  const _Float16* gb = Gin + (size_t)rclamp * HID + kg * 8;
#pragma unroll
  for (int kt = 0; kt < 4; ++kt) {
    half8 v = *(const half8*)(gb + kt * 32);   // self-loop
#pragma unroll
    for (int j = 0; j < 8; ++j) acc[kt][j] = (float)v[j];
  }

  int c = cnt[rclamp]; if (c > ELLW) c = ELLW;
  const int* erow = ell + (size_t)rclamp * ELLW;
  int k = 0;
  for (; k + 2 <= c; k += 2) {
    int2 s2 = *(const int2*)(erow + k);
    const _Float16* p0 = Gin + (size_t)s2.x * HID + kg * 8;
    const _Float16* p1 = Gin + (size_t)s2.y * HID + kg * 8;
    half8 u0 = *(const half8*)(p0 + 0);
    half8 u1 = *(const half8*)(p0 + 32);
    half8 u2 = *(const half8*)(p0 + 64);
    half8 u3 = *(const half8*)(p0 + 96);
    half8 u4 = *(const half8*)(p1 + 0);
    half8 u5 = *(const half8*)(p1 + 32);
    half8 u6 = *(const half8*)(p1 + 64);
    half8 u7 = *(const half8*)(p1 + 96);
#pragma unroll
    for (int j = 0; j < 8; ++j) {
      acc[0][j] += (float)u0[j] + (float)u4[j];
      acc[1][j] += (float)u1[j] + (float)u5[j];
      acc[2][j] += (float)u2[j] + (float)u6[j];
      acc[3][j] += (float)u3[j] + (float)u7[j];
    }
  }
  if (k < c) {
    const _Float16* p0 = Gin + (size_t)erow[k] * HID + kg * 8;
    half8 u0 = *(const half8*)(p0 + 0);
    half8 u1 = *(const half8*)(p0 + 32);
    half8 u2 = *(const half8*)(p0 + 64);
    half8 u3 = *(const half8*)(p0 + 96);
#pragma unroll
    for (int j = 0; j < 8; ++j) {
      acc[0][j] += (float)u0[j];
      acc[1][j] += (float)u1[j];
      acc[2][j] += (float)u2[j];
      acc[3][j] += (float)u3[j];
    }
  }

  // ---- h1 = relu(dis*acc + b1) in A-frag layout ----
  float sc = dis[rclamp];
  half8 a[4];
#pragma unroll
  for (int kt = 0; kt < 4; ++kt) {
    float4 bb0 = *(const float4*)&b1[kg * 8 + kt * 32];
    float4 bb1 = *(const float4*)&b1[kg * 8 + kt * 32 + 4];
    a[kt][0] = (_Float16)fmaxf(sc * acc[kt][0] + bb0.x, 0.f);
    a[kt][1] = (_Float16)fmaxf(sc * acc[kt][1] + bb0.y, 0.f);
    a[kt][2] = (_Float16)fmaxf(sc * acc[kt][2] + bb0.z, 0.f);
    a[kt][3] = (_Float16)fmaxf(sc * acc[kt][3] + bb0.w, 0.f);
    a[kt][4] = (_Float16)fmaxf(sc * acc[kt][4] + bb1.x, 0.f);
    a[kt][5] = (_Float16)fmaxf(sc * acc[kt][5] + bb1.y, 0.f);
    a[kt][6] = (_Float16)fmaxf(sc * acc[kt][6] + bb1.z, 0.f);
    a[kt][7] = (_Float16)fmaxf(sc * acc[kt][7] + bb1.w, 0.f);
  }

  // ---- per-wave MFMA: 16x128 tile ----
  const _Float16* bp = wt2 + (size_t)rloc * HID + kg * 8;
#pragma unroll
  for (int nt = 0; nt < 8; ++nt) {
    f32x4 o = (f32x4){0.f, 0.f, 0.f, 0.f};
#pragma unroll
    for (int kt = 0; kt < 4; ++kt) {
      half8 bf = *(const half8*)(bp + (size_t)nt * 16 * HID + kt * 32);
      o = __builtin_amdgcn_mfma_f32_16x16x32_f16(a[kt], bf, o, 0, 0, 0);
    }
#pragma unroll
    for (int j = 0; j < 4; ++j) {
      int orow = m0 + kg * 4 + j;
      if (orow < N) {
        Gout[(size_t)orow * HID + nt * 16 + rloc] = (_Float16)(dis[orow] * o[j]);
      }
    }
  }
}

// ---------------- gather v3 (final layer: writes h) ----------------

__global__ __launch_bounds__(256) void k_gather16v3(
    const _Float16* __restrict__ g16, const int* __restrict__ ell,
    const int* __restrict__ cnt, const float* __restrict__ dis,
    const float* __restrict__ b, _Float16* __restrict__ h16, int N) {
  int tid = blockIdx.x * blockDim.x + threadIdx.x;
  int i = tid >> 4;
  int q = tid & 15;
  if (i >= N) return;
  const _Float16* gq = g16 + q * 8;

  float acc[8];
  half8 sv = *(const half8*)(gq + (size_t)i * HID);
#pragma unroll
  for (int j = 0; j < 8; ++j) acc[j] = (float)sv[j];

  int c = cnt[i]; if (c > ELLW) c = ELLW;
  const int* row = ell + (size_t)i * ELLW;
  int k = 0;
  for (; k + 8 <= c; k += 8) {
    int4 sa = *(const int4*)(row + k);
    int4 sb = *(const int4*)(row + k + 4);
    half8 v0 = *(const half8*)(gq + (size_t)sa.x * HID);
    half8 v1 = *(const half8*)(gq + (size_t)sa.y * HID);
    half8 v2 = *(const half8*)(gq + (size_t)sa.z * HID);
    half8 v3 = *(const half8*)(gq + (size_t)sa.w * HID);
    half8 v4 = *(const half8*)(gq + (size_t)sb.x * HID);
    half8 v5 = *(const half8*)(gq + (size_t)sb.y * HID);
    half8 v6 = *(const half8*)(gq + (size_t)sb.z * HID);
    half8 v7 = *(const half8*)(gq + (size_t)sb.w * HID);
#pragma unroll
    for (int j = 0; j < 8; ++j) {
      float p01 = (float)v0[j] + (float)v1[j];
      float p23 = (float)v2[j] + (float)v3[j];
      float p45 = (float)v4[j] + (float)v5[j];
      float p67 = (float)v6[j] + (float)v7[j];
      acc[j] += (p01 + p23) + (p45 + p67);
    }
  }
  for (; k + 4 <= c; k += 4) {
    int4 s4 = *(const int4*)(row + k);
    half8 v0 = *(const half8*)(gq + (size_t)s4.x * HID);
    half8 v1 = *(const half8*)(gq + (size_t)s4.y * HID);
    half8 v2 = *(const half8*)(gq + (size_t)s4.z * HID);
    half8 v3 = *(const half8*)(gq + (size_t)s4.w * HID);
#pragma unroll
    for (int j = 0; j < 8; ++j)
      acc[j] += ((float)v0[j] + (float)v1[j]) + ((float)v2[j] + (float)v3[j]);
  }
  for (; k < c; ++k) {
    half8 v = *(const half8*)(gq + (size_t)row[k] * HID);
#pragma unroll
    for (int j = 0; j < 8; ++j) acc[j] += (float)v[j];
  }

  float sc = dis[i];
  half8 o;
#pragma unroll
  for (int j = 0; j < 8; ++j) {
    float bb = b[q * 8 + j];
    o[j] = (_Float16)fmaxf(sc * acc[j] + bb, 0.f);
  }
  *(half8*)(h16 + (size_t)i * HID + q * 8) = o;
}

// ---------------- fused pool + MLP ----------------

__device__ __forceinline__ int lower_bound_i(const int* __restrict__ a, int n, int v) {
  int lo = 0, hi = n;
  while (lo < hi) {
    int m = (lo + hi) >> 1;
    if (a[m] < v) lo = m + 1; else hi = m;
  }
  return lo;
}

__global__ __launch_bounds__(256) void k_pool_mlp(
    const _Float16* __restrict__ h16, const int* __restrict__ batch, int N,
    const float* __restrict__ Wf1, const float* __restrict__ bf1,
    const float* __restrict__ Wf2, const float* __restrict__ bf2,
    float* __restrict__ out) {
  int g = blockIdx.x;
  int t = threadIdx.x;
  int lo = lower_bound_i(batch, N, g);
  int hi = lower_bound_i(batch, N, g + 1);

  __shared__ float4 part4[256];
  __shared__ float pooled[128];
  __shared__ float dense[64];

  int col4 = t & 31;
  int roff = t >> 5;
  float4 s = make_float4(0.f, 0.f, 0.f, 0.f);
  for (int r = lo + roff; r < hi; r += 8) {
    H4v v = *(const H4v*)&h16[(size_t)r * HID + col4 * 4];
    s.x += (float)v.x; s.y += (float)v.y; s.z += (float)v.z; s.w += (float)v.w;
  }
  part4[roff * 32 + col4] = s;
  __syncthreads();

  float inv = 1.0f / fmaxf((float)(hi - lo), 1.0f);
  if (t < 32) {
    float4 tot = part4[t];
#pragma unroll
    for (int j = 1; j < 8; ++j) {
      float4 v = part4[j * 32 + t];
      tot.x += v.x; tot.y += v.y; tot.z += v.z; tot.w += v.w;
    }
    pooled[t * 4 + 0] = tot.x * inv;
    pooled[t * 4 + 1] = tot.y * inv;
    pooled[t * 4 + 2] = tot.z * inv;
    pooled[t * 4 + 3] = tot.w * inv;
  }
  __syncthreads();

  if (t < 64) {
    float a = bf1[t];
    for (int k = 0; k < 128; ++k) a += pooled[k] * Wf1[k * 64 + t];
    dense[t] = fmaxf(a, 0.f);
  }
  __syncthreads();

  if (t < 64) {
    float prod = dense[t] * Wf2[t];
#pragma unroll
    for (int off = 32; off; off >>= 1) prod += __shfl_down(prod, off);
    if (t == 0) out[g] = prod + bf2[0];
  }
}

// ---------------- launch ----------------

static inline size_t align256(size_t x) { return (x + 255) & ~(size_t)255; }

extern "C" void kernel_launch(void* const* d_in, const int* in_sizes, int n_in,
                              void* d_out, int out_size, void* d_ws, size_t ws_size,
                              hipStream_t stream) {
  const float* x = (const float*)d_in[0];
  const int* ei = (const int*)d_in[1];
  const int* batch = (const int*)d_in[2];
  const float* W0 = (const float*)d_in[3];
  const float* b0 = (const float*)d_in[4];
  const float* W1 = (const float*)d_in[5];
  const float* b1 = (const float*)d_in[6];
  const float* W2 = (const float*)d_in[7];
  const float* b2 = (const float*)d_in[8];
  const float* Wf1 = (const float*)d_in[9];
  const float* bf1 = (const float*)d_in[10];
  const float* Wf2 = (const float*)d_in[11];
  const float* bf2 = (const float*)d_in[12];
  float* out = (float*)d_out;

  const int N = in_sizes[0] / 3;
  const int E = in_sizes[1] / 2;
  const int Gn = out_size;
  const int nbuk = (N + 255) >> 8;

  const int* src = ei;
  const int* dst = ei + E;

  char* ws = (char*)d_ws;
  size_t o = 0;
  int* cnt = (int*)(ws + o); o = align256(o + (size_t)N * 4);
  float* dis = (float*)(ws + o); o = align256(o + (size_t)N * 4);
  float4* x4 = (float4*)(ws + o); o = align256(o + (size_t)N * 16);
  float4* z4 = (float4*)(ws + o); o = align256(o + (size_t)N * 16);
  int* ell = (int*)(ws + o); o = align256(o + (size_t)N * ELLW * 4);
  _Float16* g16a = (_Float16*)(ws + o); o = align256(o + (size_t)N * HID * 2);
  _Float16* g16b = (_Float16*)(ws + o); o = align256(o + (size_t)N * HID * 2);
  _Float16* wt1 = (_Float16*)(ws + o); o = align256(o + (size_t)HID * HID * 2);
  _Float16* wt2 = (_Float16*)(ws + o); o = align256(o + (size_t)HID * HID * 2);
  int* bkcnt = (int*)(ws + o); o = align256(o + (size_t)(NBINS + 1) * 4);
  int* ovfn = bkcnt + NBINS;
  unsigned* bk = (unsigned*)(ws + o); o = align256(o + (size_t)NBINS * BKCAP * 4);
  int2* ovf = (int2*)(ws + o); o = align256(o + (size_t)OVF_CAP * 8);

  const int BS = 256;
  int gN = (N + BS - 1) / BS;
  int gN16 = (int)(((long long)N * 16 + BS - 1) / BS);
  int gW2 = (2 * HID * HID + BS - 1) / BS;

  // ---- ELL build ----
  bool vec4ok = (E % 4 == 0) && (((uintptr_t)src & 15) == 0) && (((uintptr_t)dst & 15) == 0);
  if (nbuk <= NBINS) {
    k_zero_ints<<<(NBINS + 1 + BS - 1) / BS, BS, 0, stream>>>(bkcnt, NBINS + 1);
    int E4 = E / 4;
    if (E4 > 0 && vec4ok) {
      k_binA<<<(E4 + CHUNK_I4 - 1) / CHUNK_I4, 256, 0, stream>>>(
          (const int4*)src, (const int4*)dst, E4, bkcnt, bk, ovfn, ovf);
      if (E % 4) k_tail_ovf<<<1, 64, 0, stream>>>(src, dst, E4 * 4, E, ovfn, ovf);
    } else {
      k_tail_ovf<<<1, 256, 0, stream>>>(src, dst, 0, E, ovfn, ovf);
    }
    k_ell_build2<<<nbuk, 256, 0, stream>>>(bk, bkcnt, ell, cnt, N);
    k_ovf_build<<<1, 256, 0, stream>>>(ovf, ovfn, cnt, ell);
  } else {
    k_zero_ints<<<gN, BS, 0, stream>>>(cnt, N);
    k_fill_ell1<<<(E + BS - 1) / BS, BS, 0, stream>>>(src, dst, cnt, ell, E);
  }

  // ---- dis + x4 ----
  k_dis_prepx<<<gN, BS, 0, stream>>>(cnt, x, dis, x4, N);

  // ---- weight prep ----
  k_prep_w16x2<<<gW2, BS, 0, stream>>>(W1, W2, wt1, wt2);

  // ---- layer 0 aggregate ----
  k_agg3<<<gN, BS, 0, stream>>>(x4, ell, cnt, dis, z4, N);

  // ---- fused: h0 = relu(z4@W0+b0); g16a = dis * (h0 @ W1) ----
  k_l01<<<(N + 63) / 64, 256, 0, stream>>>(z4, W0, b0, wt1, dis, g16a, N);

  // ---- fused barrier-free: gather(g16a) -> h1 (A-frags); g16b = dis * (h1 @ W2) ----
  k_gg2<<<(N + 63) / 64, 256, 0, stream>>>(g16a, ell, cnt, dis, b1, wt2, g16b, N);

  // ---- final gather: h2 -> g16a (reused as h buffer) ----
  k_gather16v3<<<gN16, BS, 0, stream>>>(g16b, ell, cnt, dis, b2, g16a, N);

  // ---- fused pool + MLP ----
  k_pool_mlp<<<Gn, 256, 0, stream>>>(g16a, batch, N, Wf1, bf1, Wf2, bf2, out);
}

// Round 12
// 275.095 us; speedup vs baseline: 1.1161x; 1.1161x over previous
//
#include <hip/hip_runtime.h>

#define HID 128
#define ELLW 64

// ---- binned ELL build params ----
#define NBINS 400          // buckets of 256 dst nodes; supports N <= 102400
#define BINCAP 38          // LDS bin capacity
#define CHUNK_I4 1024      // 4096 edges per block in pass A
#define BKCAP 5120         // global bucket capacity
#define OVF_CAP 16384

typedef _Float16 half8 __attribute__((ext_vector_type(8)));
typedef float f32x4 __attribute__((ext_vector_type(4)));
struct alignas(8) H4v { _Float16 x, y, z, w; };

// ---------------- pass A: bin edges by dst>>8 with LDS staging ----------------

__global__ void k_zero_ints(int* p, int n) {
  int i = blockIdx.x * blockDim.x + threadIdx.x;
  if (i < n) p[i] = 0;
}

__device__ __forceinline__ void bin_one(int s, int d, int* lcnt, unsigned* bins,
                                        int* ovfn, int2* ovf) {
  int b = d >> 8;
  int p = atomicAdd(&lcnt[b], 1);
  if (p < BINCAP) bins[b * BINCAP + p] = ((unsigned)s << 8) | (unsigned)(d & 255);
  else { int q = atomicAdd(ovfn, 1); if (q < OVF_CAP) ovf[q] = make_int2(s, d); }
}

__global__ __launch_bounds__(256) void k_binA(
    const int4* __restrict__ src4, const int4* __restrict__ dst4, int E4,
    int* bkcnt, unsigned* __restrict__ bk, int* ovfn, int2* __restrict__ ovf) {
  __shared__ unsigned bins[NBINS * BINCAP];
  __shared__ int lcnt[NBINS];
  __shared__ int gbase[NBINS];
  int t = threadIdx.x;
  for (int b = t; b < NBINS; b += 256) lcnt[b] = 0;
  __syncthreads();

  int i0 = blockIdx.x * CHUNK_I4;
  int i1 = min(i0 + CHUNK_I4, E4);
  for (int i = i0 + t; i < i1; i += 256) {
    int4 d = dst4[i];
    int4 s = src4[i];
    bin_one(s.x, d.x, lcnt, bins, ovfn, ovf);
    bin_one(s.y, d.y, lcnt, bins, ovfn, ovf);
    bin_one(s.z, d.z, lcnt, bins, ovfn, ovf);
    bin_one(s.w, d.w, lcnt, bins, ovfn, ovf);
  }
  __syncthreads();

  for (int b = t; b < NBINS; b += 256) gbase[b] = atomicAdd(&bkcnt[b], min(lcnt[b], BINCAP));
  __syncthreads();

  int wid = t >> 6, lane = t & 63;
  for (int b = wid; b < NBINS; b += 4) {
    int c = min(lcnt[b], BINCAP);
    if (lane < c) {
      int off = gbase[b] + lane;
      unsigned r = bins[b * BINCAP + lane];
      if (off < BKCAP) bk[(size_t)b * BKCAP + off] = r;
      else {
        int q = atomicAdd(ovfn, 1);
        if (q < OVF_CAP) ovf[q] = make_int2((int)(r >> 8), b * 256 + (int)(r & 255));
      }
    }
  }
}

__global__ void k_tail_ovf(const int* __restrict__ src, const int* __restrict__ dst,
                           int e0, int E, int* ovfn, int2* __restrict__ ovf) {
  int e = e0 + threadIdx.x;
  if (e < E) {
    int q = atomicAdd(ovfn, 1);
    if (q < OVF_CAP) ovf[q] = make_int2(src[e], dst[e]);
  }
}

// ---------------- pass B: per-bucket ELL build ----------------

__global__ __launch_bounds__(256) void k_ell_build2(
    const unsigned* __restrict__ bk, const int* __restrict__ bkcnt,
    int* __restrict__ ell, int* __restrict__ cnt, int N) {
  int b = blockIdx.x;
  int t = threadIdx.x;
  __shared__ int lcnt[256];
  lcnt[t] = 0;
  __syncthreads();
  int n = bkcnt[b]; if (n > BKCAP) n = BKCAP;
  const unsigned* my = bk + (size_t)b * BKCAP;
  for (int k = t; k < n; k += 256) {
    unsigned r = my[k];
    int d0 = (int)(r & 255);
    int s = (int)(r >> 8);
    int p = atomicAdd(&lcnt[d0], 1);
    if (p < ELLW) ell[(size_t)(b * 256 + d0) * ELLW + p] = s;
  }
  __syncthreads();
  int node = b * 256 + t;
  if (node < N) cnt[node] = lcnt[t];
}

__global__ void k_ovf_build(const int2* __restrict__ ovf, const int* __restrict__ ovfn,
                            int* cnt, int* ell) {
  int n = *ovfn; if (n > OVF_CAP) n = OVF_CAP;
  for (int k = threadIdx.x; k < n; k += blockDim.x) {
    int2 e = ovf[k];
    int p = atomicAdd(&cnt[e.y], 1);
    if (p < ELLW) ell[(size_t)e.y * ELLW + p] = e.x;
  }
}

__global__ void k_fill_ell1(const int* __restrict__ src, const int* __restrict__ dst,
                            int* cnt, int* ell, int E) {
  int e = blockIdx.x * blockDim.x + threadIdx.x;
  if (e < E) {
    int d = dst[e];
    int p = atomicAdd(&cnt[d], 1);
    if (p < ELLW) ell[(size_t)d * ELLW + p] = src[e];
  }
}

// ---------------- dis + prep_x fused ----------------

__global__ void k_dis_prepx(const int* __restrict__ cnt, const float* __restrict__ x,
                            float* __restrict__ dis, float4* __restrict__ x4, int N) {
  int i = blockIdx.x * blockDim.x + threadIdx.x;
  if (i >= N) return;
  float s = rsqrtf((float)(cnt[i] + 1));
  dis[i] = s;
  x4[i] = make_float4(s * x[i * 3 + 0], s * x[i * 3 + 1], s * x[i * 3 + 2], 0.f);
}

// ---------------- layer 0 aggregate (unrolled x4) ----------------

__global__ void k_agg3(const float4* __restrict__ x4, const int* __restrict__ ell,
                       const int* __restrict__ cnt, const float* __restrict__ dis,
                       float4* __restrict__ z4, int N) {
  int i = blockIdx.x * blockDim.x + threadIdx.x;
  if (i >= N) return;
  float4 a = x4[i];
  int c = cnt[i]; if (c > ELLW) c = ELLW;
  const int* row = &ell[(size_t)i * ELLW];
  int k = 0;
  for (; k + 4 <= c; k += 4) {
    int4 s4 = *(const int4*)(row + k);
    float4 v0 = x4[s4.x], v1 = x4[s4.y], v2 = x4[s4.z], v3 = x4[s4.w];
    a.x += (v0.x + v1.x) + (v2.x + v3.x);
    a.y += (v0.y + v1.y) + (v2.y + v3.y);
    a.z += (v0.z + v1.z) + (v2.z + v3.z);
  }
  for (; k < c; ++k) {
    float4 v = x4[row[k]];
    a.x += v.x; a.y += v.y; a.z += v.z;
  }
  float s = dis[i];
  z4[i] = make_float4(s * a.x, s * a.y, s * a.z, 0.f);
}

// ---------------- both weights -> fp16 transposed [n][k] ----------------

__global__ void k_prep_w16x2(const float* __restrict__ W1, const float* __restrict__ W2,
                             _Float16* __restrict__ Wt1, _Float16* __restrict__ Wt2) {
  int idx = blockIdx.x * blockDim.x + threadIdx.x;
  if (idx >= 2 * HID * HID) return;
  int which = idx >> 14;
  int r = idx & (HID * HID - 1);
  int k = r >> 7, n = r & 127;
  const float* W = which ? W2 : W1;
  _Float16* Wt = which ? Wt2 : Wt1;
  Wt[n * HID + k] = (_Float16)W[r];
}

// ---------------- fused layer0-transform + layer1-GEMM ----------------

__global__ __launch_bounds__(256) void k_l01(
    const float4* __restrict__ z4, const float* __restrict__ W0,
    const float* __restrict__ b0, const _Float16* __restrict__ wt1,
    const float* __restrict__ dis, _Float16* __restrict__ G, int N) {
  __shared__ _Float16 hs[64][136];
  int t = threadIdx.x;
  int base = blockIdx.x * 64;

  {
    int r = t >> 2;
    int c0 = (t & 3) * 32;
    int row = base + r;
    float4 z = make_float4(0.f, 0.f, 0.f, 0.f);
    if (row < N) z = z4[row];
#pragma unroll
    for (int c = 0; c < 32; c += 4) {
      int cc = c0 + c;
      float4 w0 = *(const float4*)&W0[0 * HID + cc];
      float4 w1 = *(const float4*)&W0[1 * HID + cc];
      float4 w2 = *(const float4*)&W0[2 * HID + cc];
      float4 bb = *(const float4*)&b0[cc];
      H4v o;
      o.x = (_Float16)fmaxf(z.x * w0.x + z.y * w1.x + z.z * w2.x + bb.x, 0.f);
      o.y = (_Float16)fmaxf(z.x * w0.y + z.y * w1.y + z.z * w2.y + bb.y, 0.f);
      o.z = (_Float16)fmaxf(z.x * w0.z + z.y * w1.z + z.z * w2.z + bb.z, 0.f);
      o.w = (_Float16)fmaxf(z.x * w0.w + z.y * w1.w + z.z * w2.w + bb.w, 0.f);
      *(H4v*)&hs[r][cc] = o;
    }
  }
  __syncthreads();

  int w = t >> 6, lane = t & 63;
  int kg = lane >> 4, ccol = lane & 15;
  int lrow = w * 16 + ccol;

  f32x4 acc[8];
#pragma unroll
  for (int nt = 0; nt < 8; ++nt) acc[nt] = (f32x4){0.f, 0.f, 0.f, 0.f};

#pragma unroll
  for (int kt = 0; kt < 4; ++kt) {
    half8 a = *(const half8*)&hs[lrow][kg * 8 + kt * 32];
#pragma unroll
    for (int nt = 0; nt < 8; ++nt) {
      half8 b = *(const half8*)(wt1 + (size_t)(nt * 16 + ccol) * HID + kg * 8 + kt * 32);
      acc[nt] = __builtin_amdgcn_mfma_f32_16x16x32_f16(a, b, acc[nt], 0, 0, 0);
    }
  }

#pragma unroll
  for (int j = 0; j < 4; ++j) {
    int row = base + w * 16 + kg * 4 + j;
    if (row < N) {
      float s = dis[row];
#pragma unroll
      for (int nt = 0; nt < 8; ++nt) {
        G[(size_t)row * HID + nt * 16 + ccol] = (_Float16)(s * acc[nt][j]);
      }
    }
  }
}

// ---------------- fused gather + layer2-GEMM (round-10 LDS version) ----------------

__global__ __launch_bounds__(256) void k_gg(
    const _Float16* __restrict__ Gin, const int* __restrict__ ell,
    const int* __restrict__ cnt, const float* __restrict__ dis,
    const float* __restrict__ b, const _Float16* __restrict__ wt2,
    _Float16* __restrict__ Gout, int N) {
  __shared__ _Float16 hs[16][136];
  int t = threadIdx.x;
  int base = blockIdx.x * 16;
  int gi = t >> 4, q = t & 15;
  int i = base + gi;

  if (i < N) {
    const _Float16* gq = Gin + q * 8;
    float acc[8];
    half8 sv = *(const half8*)(gq + (size_t)i * HID);  // self-loop
#pragma unroll
    for (int j = 0; j < 8; ++j) acc[j] = (float)sv[j];

    int c = cnt[i]; if (c > ELLW) c = ELLW;
    const int* row = ell + (size_t)i * ELLW;
    int k = 0;
    for (; k + 8 <= c; k += 8) {
      int4 sa = *(const int4*)(row + k);
      int4 sb = *(const int4*)(row + k + 4);
      half8 v0 = *(const half8*)(gq + (size_t)sa.x * HID);
      half8 v1 = *(const half8*)(gq + (size_t)sa.y * HID);
      half8 v2 = *(const half8*)(gq + (size_t)sa.z * HID);
      half8 v3 = *(const half8*)(gq + (size_t)sa.w * HID);
      half8 v4 = *(const half8*)(gq + (size_t)sb.x * HID);
      half8 v5 = *(const half8*)(gq + (size_t)sb.y * HID);
      half8 v6 = *(const half8*)(gq + (size_t)sb.z * HID);
      half8 v7 = *(const half8*)(gq + (size_t)sb.w * HID);
#pragma unroll
      for (int j = 0; j < 8; ++j) {
        float p01 = (float)v0[j] + (float)v1[j];
        float p23 = (float)v2[j] + (float)v3[j];
        float p45 = (float)v4[j] + (float)v5[j];
        float p67 = (float)v6[j] + (float)v7[j];
        acc[j] += (p01 + p23) + (p45 + p67);
      }
    }
    for (; k + 4 <= c; k += 4) {
      int4 s4 = *(const int4*)(row + k);
      half8 v0 = *(const half8*)(gq + (size_t)s4.x * HID);
      half8 v1 = *(const half8*)(gq + (size_t)s4.y * HID);
      half8 v2 = *(const half8*)(gq + (size_t)s4.z * HID);
      half8 v3 = *(const half8*)(gq + (size_t)s4.w * HID);
#pragma unroll
      for (int j = 0; j < 8; ++j)
        acc[j] += ((float)v0[j] + (float)v1[j]) + ((float)v2[j] + (float)v3[j]);
    }
    for (; k < c; ++k) {
      half8 v = *(const half8*)(gq + (size_t)row[k] * HID);
#pragma unroll
      for (int j = 0; j < 8; ++j) acc[j] += (float)v[j];
    }

    float sc = dis[i];
    half8 o;
#pragma unroll
    for (int j = 0; j < 8; ++j) {
      float bb = b[q * 8 + j];
      o[j] = (_Float16)fmaxf(sc * acc[j] + bb, 0.f);
    }
    *(half8*)&hs[gi][q * 8] = o;
  } else {
    half8 zo;
#pragma unroll
    for (int j = 0; j < 8; ++j) zo[j] = (_Float16)0.f;
    *(half8*)&hs[gi][q * 8] = zo;
  }
  __syncthreads();

  // MFMA: wave w covers col-tiles {2w, 2w+1}
  int w = t >> 6, lane = t & 63;
  int kg = lane >> 4, ccol = lane & 15;
  f32x4 acc2[2];
  acc2[0] = (f32x4){0.f, 0.f, 0.f, 0.f};
  acc2[1] = (f32x4){0.f, 0.f, 0.f, 0.f};

#pragma unroll
  for (int kt = 0; kt < 4; ++kt) {
    half8 a = *(const half8*)&hs[ccol][kg * 8 + kt * 32];
#pragma unroll
    for (int ntl = 0; ntl < 2; ++ntl) {
      int n = (2 * w + ntl) * 16 + ccol;
      half8 bf = *(const half8*)(wt2 + (size_t)n * HID + kg * 8 + kt * 32);
      acc2[ntl] = __builtin_amdgcn_mfma_f32_16x16x32_f16(a, bf, acc2[ntl], 0, 0, 0);
    }
  }

#pragma unroll
  for (int j = 0; j < 4; ++j) {
    int row = base + kg * 4 + j;
    if (row < N) {
      float s = dis[row];
#pragma unroll
      for (int ntl = 0; ntl < 2; ++ntl) {
        Gout[(size_t)row * HID + (2 * w + ntl) * 16 + ccol] = (_Float16)(s * acc2[ntl][j]);
      }
    }
  }
}

// ---------------- final gather fused with mean-pool accumulation ----------------
// v3 gather body (identical access pattern); h2 never hits HBM. Per 16-row block:
// per graph-slot LDS column-reduce + 128 atomicAdds into pool[Gn][128].

__global__ __launch_bounds__(256) void k_gather_pool(
    const _Float16* __restrict__ g16, const int* __restrict__ ell,
    const int* __restrict__ cnt, const float* __restrict__ dis,
    const float* __restrict__ b, const int* __restrict__ batch,
    float* __restrict__ pool, int N) {
  __shared__ float part[16][132];
  int t = threadIdx.x;
  int base = blockIdx.x * 16;
  int gi = t >> 4, q = t & 15;
  int i = base + gi;
  bool valid = (i < N);
  int iclamp = valid ? i : (N - 1);

  float acc[8];
  {
    const _Float16* gq = g16 + q * 8;
    half8 sv = *(const half8*)(gq + (size_t)iclamp * HID);  // self-loop
#pragma unroll
    for (int j = 0; j < 8; ++j) acc[j] = (float)sv[j];

    int c = cnt[iclamp]; if (c > ELLW) c = ELLW;
    const int* row = ell + (size_t)iclamp * ELLW;
    int k = 0;
    for (; k + 8 <= c; k += 8) {
      int4 sa = *(const int4*)(row + k);
      int4 sb = *(const int4*)(row + k + 4);
      half8 v0 = *(const half8*)(gq + (size_t)sa.x * HID);
      half8 v1 = *(const half8*)(gq + (size_t)sa.y * HID);
      half8 v2 = *(const half8*)(gq + (size_t)sa.z * HID);
      half8 v3 = *(const half8*)(gq + (size_t)sa.w * HID);
      half8 v4 = *(const half8*)(gq + (size_t)sb.x * HID);
      half8 v5 = *(const half8*)(gq + (size_t)sb.y * HID);
      half8 v6 = *(const half8*)(gq + (size_t)sb.z * HID);
      half8 v7 = *(const half8*)(gq + (size_t)sb.w * HID);
#pragma unroll
      for (int j = 0; j < 8; ++j) {
        float p01 = (float)v0[j] + (float)v1[j];
        float p23 = (float)v2[j] + (float)v3[j];
        float p45 = (float)v4[j] + (float)v5[j];
        float p67 = (float)v6[j] + (float)v7[j];
        acc[j] += (p01 + p23) + (p45 + p67);
      }
    }
    for (; k + 4 <= c; k += 4) {
      int4 s4 = *(const int4*)(row + k);
      half8 v0 = *(const half8*)(gq + (size_t)s4.x * HID);
      half8 v1 = *(const half8*)(gq + (size_t)s4.y * HID);
      half8 v2 = *(const half8*)(gq + (size_t)s4.z * HID);
      half8 v3 = *(const half8*)(gq + (size_t)s4.w * HID);
#pragma unroll
      for (int j = 0; j < 8; ++j)
        acc[j] += ((float)v0[j] + (float)v1[j]) + ((float)v2[j] + (float)v3[j]);
    }
    for (; k < c; ++k) {
      half8 v = *(const half8*)(gq + (size_t)row[k] * HID);
#pragma unroll
      for (int j = 0; j < 8; ++j) acc[j] += (float)v[j];
    }

    float sc = dis[iclamp];
#pragma unroll
    for (int j = 0; j < 8; ++j) {
      float bb = b[q * 8 + j];
      acc[j] = fmaxf(sc * acc[j] + bb, 0.f);
    }
  }

  // ---- pool accumulation (batch sorted => block spans few graphs) ----
  int g0 = batch[base];                         // base < N always
  int g1 = batch[(base + 15 < N) ? base + 15 : N - 1];
  int mybg = valid ? batch[i] : -1;

  for (int s = g0; s <= g1; ++s) {
    bool m = (mybg == s);
#pragma unroll
    for (int j = 0; j < 8; ++j) part[gi][q * 8 + j] = m ? acc[j] : 0.f;
    __syncthreads();
    if (t < 128) {
      float v = 0.f;
#pragma unroll
      for (int r = 0; r < 16; ++r) v += part[r][t];
      if (v != 0.f) atomicAdd(&pool[s * HID + t], v);
    }
    __syncthreads();
  }
}

// ---------------- MLP head: out[g] = relu(mean@Wf1+bf1)@Wf2 + bf2 ----------------

__device__ __forceinline__ int lower_bound_i(const int* __restrict__ a, int n, int v) {
  int lo = 0, hi = n;
  while (lo < hi) {
    int m = (lo + hi) >> 1;
    if (a[m] < v) lo = m + 1; else hi = m;
  }
  return lo;
}

__global__ __launch_bounds__(64) void k_mlp512(
    const float* __restrict__ pool, const int* __restrict__ batch, int N,
    const float* __restrict__ Wf1, const float* __restrict__ bf1,
    const float* __restrict__ Wf2, const float* __restrict__ bf2,
    float* __restrict__ out) {
  int g = blockIdx.x;
  int lane = threadIdx.x;
  int lo = lower_bound_i(batch, N, g);
  int hi = lower_bound_i(batch, N, g + 1);
  float inv = 1.0f / fmaxf((float)(hi - lo), 1.0f);

  __shared__ float p[128];
  p[lane] = pool[g * HID + lane] * inv;
  p[lane + 64] = pool[g * HID + 64 + lane] * inv;
  __syncthreads();

  float a = bf1[lane];
  for (int k = 0; k < 128; ++k) a += p[k] * Wf1[k * 64 + lane];
  a = fmaxf(a, 0.f);
  float prod = a * Wf2[lane];
#pragma unroll
  for (int off = 32; off; off >>= 1) prod += __shfl_down(prod, off);
  if (lane == 0) out[g] = prod + bf2[0];
}

// ---------------- launch ----------------

static inline size_t align256(size_t x) { return (x + 255) & ~(size_t)255; }

extern "C" void kernel_launch(void* const* d_in, const int* in_sizes, int n_in,
                              void* d_out, int out_size, void* d_ws, size_t ws_size,
                              hipStream_t stream) {
  const float* x = (const float*)d_in[0];
  const int* ei = (const int*)d_in[1];
  const int* batch = (const int*)d_in[2];
  const float* W0 = (const float*)d_in[3];
  const float* b0 = (const float*)d_in[4];
  const float* W1 = (const float*)d_in[5];
  const float* b1 = (const float*)d_in[6];
  const float* W2 = (const float*)d_in[7];
  const float* b2 = (const float*)d_in[8];
  const float* Wf1 = (const float*)d_in[9];
  const float* bf1 = (const float*)d_in[10];
  const float* Wf2 = (const float*)d_in[11];
  const float* bf2 = (const float*)d_in[12];
  float* out = (float*)d_out;

  const int N = in_sizes[0] / 3;
  const int E = in_sizes[1] / 2;
  const int Gn = out_size;
  const int nbuk = (N + 255) >> 8;

  const int* src = ei;
  const int* dst = ei + E;

  char* ws = (char*)d_ws;
  size_t o = 0;
  int* cnt = (int*)(ws + o); o = align256(o + (size_t)N * 4);
  float* dis = (float*)(ws + o); o = align256(o + (size_t)N * 4);
  float4* x4 = (float4*)(ws + o); o = align256(o + (size_t)N * 16);
  float4* z4 = (float4*)(ws + o); o = align256(o + (size_t)N * 16);
  int* ell = (int*)(ws + o); o = align256(o + (size_t)N * ELLW * 4);
  _Float16* g16a = (_Float16*)(ws + o); o = align256(o + (size_t)N * HID * 2);
  _Float16* g16b = (_Float16*)(ws + o); o = align256(o + (size_t)N * HID * 2);
  _Float16* wt1 = (_Float16*)(ws + o); o = align256(o + (size_t)HID * HID * 2);
  _Float16* wt2 = (_Float16*)(ws + o); o = align256(o + (size_t)HID * HID * 2);
  // bkcnt(+ovfn) and pool adjacent -> single zeroing launch covers both
  size_t zero_base = o;
  int* bkcnt = (int*)(ws + o); o = align256(o + (size_t)(NBINS + 1) * 4);
  int* ovfn = bkcnt + NBINS;
  float* pool = (float*)(ws + o); o = align256(o + (size_t)Gn * HID * 4);
  size_t zero_bytes = o - zero_base;
  unsigned* bk = (unsigned*)(ws + o); o = align256(o + (size_t)NBINS * BKCAP * 4);
  int2* ovf = (int2*)(ws + o); o = align256(o + (size_t)OVF_CAP * 8);

  const int BS = 256;
  int gN = (N + BS - 1) / BS;
  int gW2 = (2 * HID * HID + BS - 1) / BS;
  int zn = (int)(zero_bytes / 4);

  // ---- zero bkcnt + ovfn + pool in one launch ----
  k_zero_ints<<<(zn + BS - 1) / BS, BS, 0, stream>>>((int*)(ws + zero_base), zn);

  // ---- ELL build ----
  bool vec4ok = (E % 4 == 0) && (((uintptr_t)src & 15) == 0) && (((uintptr_t)dst & 15) == 0);
  if (nbuk <= NBINS) {
    int E4 = E / 4;
    if (E4 > 0 && vec4ok) {
      k_binA<<<(E4 + CHUNK_I4 - 1) / CHUNK_I4, 256, 0, stream>>>(
          (const int4*)src, (const int4*)dst, E4, bkcnt, bk, ovfn, ovf);
      if (E % 4) k_tail_ovf<<<1, 64, 0, stream>>>(src, dst, E4 * 4, E, ovfn, ovf);
    } else {
      k_tail_ovf<<<1, 256, 0, stream>>>(src, dst, 0, E, ovfn, ovf);
    }
    k_ell_build2<<<nbuk, 256, 0, stream>>>(bk, bkcnt, ell, cnt, N);
    k_ovf_build<<<1, 256, 0, stream>>>(ovf, ovfn, cnt, ell);
  } else {
    k_zero_ints<<<gN, BS, 0, stream>>>(cnt, N);
    k_fill_ell1<<<(E + BS - 1) / BS, BS, 0, stream>>>(src, dst, cnt, ell, E);
  }

  // ---- dis + x4 ----
  k_dis_prepx<<<gN, BS, 0, stream>>>(cnt, x, dis, x4, N);

  // ---- weight prep ----
  k_prep_w16x2<<<gW2, BS, 0, stream>>>(W1, W2, wt1, wt2);

  // ---- layer 0 aggregate ----
  k_agg3<<<gN, BS, 0, stream>>>(x4, ell, cnt, dis, z4, N);

  // ---- fused: h0 = relu(z4@W0+b0); g16a = dis * (h0 @ W1) ----
  k_l01<<<(N + 63) / 64, 256, 0, stream>>>(z4, W0, b0, wt1, dis, g16a, N);

  // ---- fused: gather(g16a) -> h1 (LDS); g16b = dis * (h1 @ W2) ----
  k_gg<<<(N + 15) / 16, 256, 0, stream>>>(g16a, ell, cnt, dis, b1, wt2, g16b, N);

  // ---- final gather fused with pool accumulation ----
  k_gather_pool<<<(N + 15) / 16, 256, 0, stream>>>(g16b, ell, cnt, dis, b2, batch, pool, N);

  // ---- MLP head ----
  k_mlp512<<<Gn, 64, 0, stream>>>(pool, batch, N, Wf1, bf1, Wf2, bf2, out);
}

// Round 13
// 270.596 us; speedup vs baseline: 1.1347x; 1.0166x over previous
//
#include <hip/hip_runtime.h>

#define HID 128
#define ELLW 64

// ---- binned ELL build params ----
#define NBINS 400          // buckets of 256 dst nodes; supports N <= 102400
#define BINCAP 38          // LDS bin capacity
#define CHUNK_I4 1024      // 4096 edges per block in pass A
#define BKCAP 5120         // global bucket capacity
#define OVF_CAP 16384

typedef _Float16 half8 __attribute__((ext_vector_type(8)));
typedef float f32x4 __attribute__((ext_vector_type(4)));
struct alignas(8) H4v { _Float16 x, y, z, w; };

// ---------------- pass A: bin edges by dst>>8 with LDS staging ----------------

__global__ void k_zero_ints(int* p, int n) {
  int i = blockIdx.x * blockDim.x + threadIdx.x;
  if (i < n) p[i] = 0;
}

__device__ __forceinline__ void bin_one(int s, int d, int* lcnt, unsigned* bins,
                                        int* ovfn, int2* ovf) {
  int b = d >> 8;
  int p = atomicAdd(&lcnt[b], 1);
  if (p < BINCAP) bins[b * BINCAP + p] = ((unsigned)s << 8) | (unsigned)(d & 255);
  else { int q = atomicAdd(ovfn, 1); if (q < OVF_CAP) ovf[q] = make_int2(s, d); }
}

__global__ __launch_bounds__(256) void k_binA(
    const int4* __restrict__ src4, const int4* __restrict__ dst4, int E4,
    int* bkcnt, unsigned* __restrict__ bk, int* ovfn, int2* __restrict__ ovf) {
  __shared__ unsigned bins[NBINS * BINCAP];
  __shared__ int lcnt[NBINS];
  __shared__ int gbase[NBINS];
  int t = threadIdx.x;
  for (int b = t; b < NBINS; b += 256) lcnt[b] = 0;
  __syncthreads();

  int i0 = blockIdx.x * CHUNK_I4;
  int i1 = min(i0 + CHUNK_I4, E4);
  for (int i = i0 + t; i < i1; i += 256) {
    int4 d = dst4[i];
    int4 s = src4[i];
    bin_one(s.x, d.x, lcnt, bins, ovfn, ovf);
    bin_one(s.y, d.y, lcnt, bins, ovfn, ovf);
    bin_one(s.z, d.z, lcnt, bins, ovfn, ovf);
    bin_one(s.w, d.w, lcnt, bins, ovfn, ovf);
  }
  __syncthreads();

  for (int b = t; b < NBINS; b += 256) gbase[b] = atomicAdd(&bkcnt[b], min(lcnt[b], BINCAP));
  __syncthreads();

  int wid = t >> 6, lane = t & 63;
  for (int b = wid; b < NBINS; b += 4) {
    int c = min(lcnt[b], BINCAP);
    if (lane < c) {
      int off = gbase[b] + lane;
      unsigned r = bins[b * BINCAP + lane];
      if (off < BKCAP) bk[(size_t)b * BKCAP + off] = r;
      else {
        int q = atomicAdd(ovfn, 1);
        if (q < OVF_CAP) ovf[q] = make_int2((int)(r >> 8), b * 256 + (int)(r & 255));
      }
    }
  }
}

__global__ void k_tail_ovf(const int* __restrict__ src, const int* __restrict__ dst,
                           int e0, int E, int* ovfn, int2* __restrict__ ovf) {
  int e = e0 + threadIdx.x;
  if (e < E) {
    int q = atomicAdd(ovfn, 1);
    if (q < OVF_CAP) ovf[q] = make_int2(src[e], dst[e]);
  }
}

// ---------------- pass B: per-bucket ELL build ----------------

__global__ __launch_bounds__(256) void k_ell_build2(
    const unsigned* __restrict__ bk, const int* __restrict__ bkcnt,
    int* __restrict__ ell, int* __restrict__ cnt, int N) {
  int b = blockIdx.x;
  int t = threadIdx.x;
  __shared__ int lcnt[256];
  lcnt[t] = 0;
  __syncthreads();
  int n = bkcnt[b]; if (n > BKCAP) n = BKCAP;
  const unsigned* my = bk + (size_t)b * BKCAP;
  for (int k = t; k < n; k += 256) {
    unsigned r = my[k];
    int d0 = (int)(r & 255);
    int s = (int)(r >> 8);
    int p = atomicAdd(&lcnt[d0], 1);
    if (p < ELLW) ell[(size_t)(b * 256 + d0) * ELLW + p] = s;
  }
  __syncthreads();
  int node = b * 256 + t;
  if (node < N) cnt[node] = lcnt[t];
}

__global__ void k_ovf_build(const int2* __restrict__ ovf, const int* __restrict__ ovfn,
                            int* cnt, int* ell) {
  int n = *ovfn; if (n > OVF_CAP) n = OVF_CAP;
  for (int k = threadIdx.x; k < n; k += blockDim.x) {
    int2 e = ovf[k];
    int p = atomicAdd(&cnt[e.y], 1);
    if (p < ELLW) ell[(size_t)e.y * ELLW + p] = e.x;
  }
}

__global__ void k_fill_ell1(const int* __restrict__ src, const int* __restrict__ dst,
                            int* cnt, int* ell, int E) {
  int e = blockIdx.x * blockDim.x + threadIdx.x;
  if (e < E) {
    int d = dst[e];
    int p = atomicAdd(&cnt[d], 1);
    if (p < ELLW) ell[(size_t)d * ELLW + p] = src[e];
  }
}

// ---------------- dis + prep_x fused ----------------

__global__ void k_dis_prepx(const int* __restrict__ cnt, const float* __restrict__ x,
                            float* __restrict__ dis, float4* __restrict__ x4, int N) {
  int i = blockIdx.x * blockDim.x + threadIdx.x;
  if (i >= N) return;
  float s = rsqrtf((float)(cnt[i] + 1));
  dis[i] = s;
  x4[i] = make_float4(s * x[i * 3 + 0], s * x[i * 3 + 1], s * x[i * 3 + 2], 0.f);
}

// ---------------- layer 0 aggregate (unrolled x4) ----------------

__global__ void k_agg3(const float4* __restrict__ x4, const int* __restrict__ ell,
                       const int* __restrict__ cnt, const float* __restrict__ dis,
                       float4* __restrict__ z4, int N) {
  int i = blockIdx.x * blockDim.x + threadIdx.x;
  if (i >= N) return;
  float4 a = x4[i];
  int c = cnt[i]; if (c > ELLW) c = ELLW;
  const int* row = &ell[(size_t)i * ELLW];
  int k = 0;
  for (; k + 4 <= c; k += 4) {
    int4 s4 = *(const int4*)(row + k);
    float4 v0 = x4[s4.x], v1 = x4[s4.y], v2 = x4[s4.z], v3 = x4[s4.w];
    a.x += (v0.x + v1.x) + (v2.x + v3.x);
    a.y += (v0.y + v1.y) + (v2.y + v3.y);
    a.z += (v0.z + v1.z) + (v2.z + v3.z);
  }
  for (; k < c; ++k) {
    float4 v = x4[row[k]];
    a.x += v.x; a.y += v.y; a.z += v.z;
  }
  float s = dis[i];
  z4[i] = make_float4(s * a.x, s * a.y, s * a.z, 0.f);
}

// ---------------- both weights -> fp16 transposed [n][k] ----------------

__global__ void k_prep_w16x2(const float* __restrict__ W1, const float* __restrict__ W2,
                             _Float16* __restrict__ Wt1, _Float16* __restrict__ Wt2) {
  int idx = blockIdx.x * blockDim.x + threadIdx.x;
  if (idx >= 2 * HID * HID) return;
  int which = idx >> 14;
  int r = idx & (HID * HID - 1);
  int k = r >> 7, n = r & 127;
  const float* W = which ? W2 : W1;
  _Float16* Wt = which ? Wt2 : Wt1;
  Wt[n * HID + k] = (_Float16)W[r];
}

// ---------------- fused layer0-transform + layer1-GEMM ----------------

__global__ __launch_bounds__(256) void k_l01(
    const float4* __restrict__ z4, const float* __restrict__ W0,
    const float* __restrict__ b0, const _Float16* __restrict__ wt1,
    const float* __restrict__ dis, _Float16* __restrict__ G, int N) {
  __shared__ _Float16 hs[64][136];
  int t = threadIdx.x;
  int base = blockIdx.x * 64;

  {
    int r = t >> 2;
    int c0 = (t & 3) * 32;
    int row = base + r;
    float4 z = make_float4(0.f, 0.f, 0.f, 0.f);
    if (row < N) z = z4[row];
#pragma unroll
    for (int c = 0; c < 32; c += 4) {
      int cc = c0 + c;
      float4 w0 = *(const float4*)&W0[0 * HID + cc];
      float4 w1 = *(const float4*)&W0[1 * HID + cc];
      float4 w2 = *(const float4*)&W0[2 * HID + cc];
      float4 bb = *(const float4*)&b0[cc];
      H4v o;
      o.x = (_Float16)fmaxf(z.x * w0.x + z.y * w1.x + z.z * w2.x + bb.x, 0.f);
      o.y = (_Float16)fmaxf(z.x * w0.y + z.y * w1.y + z.z * w2.y + bb.y, 0.f);
      o.z = (_Float16)fmaxf(z.x * w0.z + z.y * w1.z + z.z * w2.z + bb.z, 0.f);
      o.w = (_Float16)fmaxf(z.x * w0.w + z.y * w1.w + z.z * w2.w + bb.w, 0.f);
      *(H4v*)&hs[r][cc] = o;
    }
  }
  __syncthreads();

  int w = t >> 6, lane = t & 63;
  int kg = lane >> 4, ccol = lane & 15;
  int lrow = w * 16 + ccol;

  f32x4 acc[8];
#pragma unroll
  for (int nt = 0; nt < 8; ++nt) acc[nt] = (f32x4){0.f, 0.f, 0.f, 0.f};

#pragma unroll
  for (int kt = 0; kt < 4; ++kt) {
    half8 a = *(const half8*)&hs[lrow][kg * 8 + kt * 32];
#pragma unroll
    for (int nt = 0; nt < 8; ++nt) {
      half8 b = *(const half8*)(wt1 + (size_t)(nt * 16 + ccol) * HID + kg * 8 + kt * 32);
      acc[nt] = __builtin_amdgcn_mfma_f32_16x16x32_f16(a, b, acc[nt], 0, 0, 0);
    }
  }

#pragma unroll
  for (int j = 0; j < 4; ++j) {
    int row = base + w * 16 + kg * 4 + j;
    if (row < N) {
      float s = dis[row];
#pragma unroll
      for (int nt = 0; nt < 8; ++nt) {
        G[(size_t)row * HID + nt * 16 + ccol] = (_Float16)(s * acc[nt][j]);
      }
    }
  }
}

// ---------------- layer-1 gather (pure, v3 structure) ----------------
// q1[i] = dis[i] * relu(dis[i] * (g16a[i] + sum_nbr g16a) + b1)
// (the extra dis[i] factor is layer-2's src-side normalization, commuted past W2)

__global__ __launch_bounds__(256) void k_g1(
    const _Float16* __restrict__ g16, const int* __restrict__ ell,
    const int* __restrict__ cnt, const float* __restrict__ dis,
    const float* __restrict__ b, _Float16* __restrict__ q1, int N) {
  int tid = blockIdx.x * blockDim.x + threadIdx.x;
  int i = tid >> 4;
  int q = tid & 15;
  if (i >= N) return;
  const _Float16* gq = g16 + q * 8;

  float acc[8];
  half8 sv = *(const half8*)(gq + (size_t)i * HID);
#pragma unroll
  for (int j = 0; j < 8; ++j) acc[j] = (float)sv[j];

  int c = cnt[i]; if (c > ELLW) c = ELLW;
  const int* row = ell + (size_t)i * ELLW;
  int k = 0;
  for (; k + 8 <= c; k += 8) {
    int4 sa = *(const int4*)(row + k);
    int4 sb = *(const int4*)(row + k + 4);
    half8 v0 = *(const half8*)(gq + (size_t)sa.x * HID);
    half8 v1 = *(const half8*)(gq + (size_t)sa.y * HID);
    half8 v2 = *(const half8*)(gq + (size_t)sa.z * HID);
    half8 v3 = *(const half8*)(gq + (size_t)sa.w * HID);
    half8 v4 = *(const half8*)(gq + (size_t)sb.x * HID);
    half8 v5 = *(const half8*)(gq + (size_t)sb.y * HID);
    half8 v6 = *(const half8*)(gq + (size_t)sb.z * HID);
    half8 v7 = *(const half8*)(gq + (size_t)sb.w * HID);
#pragma unroll
    for (int j = 0; j < 8; ++j) {
      float p01 = (float)v0[j] + (float)v1[j];
      float p23 = (float)v2[j] + (float)v3[j];
      float p45 = (float)v4[j] + (float)v5[j];
      float p67 = (float)v6[j] + (float)v7[j];
      acc[j] += (p01 + p23) + (p45 + p67);
    }
  }
  for (; k + 4 <= c; k += 4) {
    int4 s4 = *(const int4*)(row + k);
    half8 v0 = *(const half8*)(gq + (size_t)s4.x * HID);
    half8 v1 = *(const half8*)(gq + (size_t)s4.y * HID);
    half8 v2 = *(const half8*)(gq + (size_t)s4.z * HID);
    half8 v3 = *(const half8*)(gq + (size_t)s4.w * HID);
#pragma unroll
    for (int j = 0; j < 8; ++j)
      acc[j] += ((float)v0[j] + (float)v1[j]) + ((float)v2[j] + (float)v3[j]);
  }
  for (; k < c; ++k) {
    half8 v = *(const half8*)(gq + (size_t)row[k] * HID);
#pragma unroll
    for (int j = 0; j < 8; ++j) acc[j] += (float)v[j];
  }

  float sc = dis[i];
  half8 o;
#pragma unroll
  for (int j = 0; j < 8; ++j) {
    float bb = b[q * 8 + j];
    o[j] = (_Float16)(sc * fmaxf(sc * acc[j] + bb, 0.f));
  }
  *(half8*)(q1 + (size_t)i * HID + q * 8) = o;
}

// ---------------- final: gather(q1) -> v=dis*agg -> MFMA W2 -> relu+b2 -> pool ------
// v3 gather body; one barrier; C-frag masked shfl-reduce; atomics into pool.

__global__ __launch_bounds__(256) void k_gpool2(
    const _Float16* __restrict__ q1, const int* __restrict__ ell,
    const int* __restrict__ cnt, const float* __restrict__ dis,
    const float* __restrict__ b2, const _Float16* __restrict__ wt2,
    const int* __restrict__ batch, float* __restrict__ pool, int N) {
  __shared__ _Float16 hs[16][136];
  int t = threadIdx.x;
  int base = blockIdx.x * 16;
  int gi = t >> 4, q = t & 15;
  int i = base + gi;

  if (i < N) {
    const _Float16* gq = q1 + q * 8;
    float acc[8];
    half8 sv = *(const half8*)(gq + (size_t)i * HID);
#pragma unroll
    for (int j = 0; j < 8; ++j) acc[j] = (float)sv[j];

    int c = cnt[i]; if (c > ELLW) c = ELLW;
    const int* row = ell + (size_t)i * ELLW;
    int k = 0;
    for (; k + 8 <= c; k += 8) {
      int4 sa = *(const int4*)(row + k);
      int4 sb = *(const int4*)(row + k + 4);
      half8 v0 = *(const half8*)(gq + (size_t)sa.x * HID);
      half8 v1 = *(const half8*)(gq + (size_t)sa.y * HID);
      half8 v2 = *(const half8*)(gq + (size_t)sa.z * HID);
      half8 v3 = *(const half8*)(gq + (size_t)sa.w * HID);
      half8 v4 = *(const half8*)(gq + (size_t)sb.x * HID);
      half8 v5 = *(const half8*)(gq + (size_t)sb.y * HID);
      half8 v6 = *(const half8*)(gq + (size_t)sb.z * HID);
      half8 v7 = *(const half8*)(gq + (size_t)sb.w * HID);
#pragma unroll
      for (int j = 0; j < 8; ++j) {
        float p01 = (float)v0[j] + (float)v1[j];
        float p23 = (float)v2[j] + (float)v3[j];
        float p45 = (float)v4[j] + (float)v5[j];
        float p67 = (float)v6[j] + (float)v7[j];
        acc[j] += (p01 + p23) + (p45 + p67);
      }
    }
    for (; k + 4 <= c; k += 4) {
      int4 s4 = *(const int4*)(row + k);
      half8 v0 = *(const half8*)(gq + (size_t)s4.x * HID);
      half8 v1 = *(const half8*)(gq + (size_t)s4.y * HID);
      half8 v2 = *(const half8*)(gq + (size_t)s4.z * HID);
      half8 v3 = *(const half8*)(gq + (size_t)s4.w * HID);
#pragma unroll
      for (int j = 0; j < 8; ++j)
        acc[j] += ((float)v0[j] + (float)v1[j]) + ((float)v2[j] + (float)v3[j]);
    }
    for (; k < c; ++k) {
      half8 v = *(const half8*)(gq + (size_t)row[k] * HID);
#pragma unroll
      for (int j = 0; j < 8; ++j) acc[j] += (float)v[j];
    }

    float sc = dis[i];
    half8 o;
#pragma unroll
    for (int j = 0; j < 8; ++j) o[j] = (_Float16)(sc * acc[j]);
    *(half8*)&hs[gi][q * 8] = o;
  } else {
    half8 zo;
#pragma unroll
    for (int j = 0; j < 8; ++j) zo[j] = (_Float16)0.f;
    *(half8*)&hs[gi][q * 8] = zo;
  }
  __syncthreads();

  // ---- MFMA: wave w covers col-tiles {2w, 2w+1} of the 16x128 output tile ----
  int w = t >> 6, lane = t & 63;
  int kg = lane >> 4, rloc = lane & 15;
  f32x4 acc2[2];
  acc2[0] = (f32x4){0.f, 0.f, 0.f, 0.f};
  acc2[1] = (f32x4){0.f, 0.f, 0.f, 0.f};

#pragma unroll
  for (int kt = 0; kt < 4; ++kt) {
    half8 a = *(const half8*)&hs[rloc][kg * 8 + kt * 32];
#pragma unroll
    for (int ntl = 0; ntl < 2; ++ntl) {
      int n = (2 * w + ntl) * 16 + rloc;
      half8 bf = *(const half8*)(wt2 + (size_t)n * HID + kg * 8 + kt * 32);
      acc2[ntl] = __builtin_amdgcn_mfma_f32_16x16x32_f16(a, bf, acc2[ntl], 0, 0, 0);
    }
  }

  // ---- h2 = relu(v@W2 + b2); masked per-graph reduce in-register; pool atomics ----
  float v2[2][4];
#pragma unroll
  for (int ntl = 0; ntl < 2; ++ntl) {
    int col = (2 * w + ntl) * 16 + rloc;
    float bb = b2[col];
#pragma unroll
    for (int j = 0; j < 4; ++j) v2[ntl][j] = fmaxf(acc2[ntl][j] + bb, 0.f);
  }
  int brow[4];
#pragma unroll
  for (int j = 0; j < 4; ++j) {
    int row = base + kg * 4 + j;
    brow[j] = (row < N) ? batch[row] : -1;
  }
  int g0 = batch[base];
  int lastr = base + 15; if (lastr >= N) lastr = N - 1;
  int g1 = batch[lastr];

  for (int s = g0; s <= g1; ++s) {
#pragma unroll
    for (int ntl = 0; ntl < 2; ++ntl) {
      float p = 0.f;
#pragma unroll
      for (int j = 0; j < 4; ++j) p += (brow[j] == s) ? v2[ntl][j] : 0.f;
      p += __shfl_xor(p, 16);
      p += __shfl_xor(p, 32);
      if (kg == 0 && p != 0.f) {
        atomicAdd(&pool[s * HID + (2 * w + ntl) * 16 + rloc], p);
      }
    }
  }
}

// ---------------- MLP head: out[g] = relu(mean@Wf1+bf1)@Wf2 + bf2 ----------------

__device__ __forceinline__ int lower_bound_i(const int* __restrict__ a, int n, int v) {
  int lo = 0, hi = n;
  while (lo < hi) {
    int m = (lo + hi) >> 1;
    if (a[m] < v) lo = m + 1; else hi = m;
  }
  return lo;
}

__global__ __launch_bounds__(64) void k_mlp512(
    const float* __restrict__ pool, const int* __restrict__ batch, int N,
    const float* __restrict__ Wf1, const float* __restrict__ bf1,
    const float* __restrict__ Wf2, const float* __restrict__ bf2,
    float* __restrict__ out) {
  int g = blockIdx.x;
  int lane = threadIdx.x;
  int lo = lower_bound_i(batch, N, g);
  int hi = lower_bound_i(batch, N, g + 1);
  float inv = 1.0f / fmaxf((float)(hi - lo), 1.0f);

  __shared__ float p[128];
  p[lane] = pool[g * HID + lane] * inv;
  p[lane + 64] = pool[g * HID + 64 + lane] * inv;
  __syncthreads();

  float a = bf1[lane];
  for (int k = 0; k < 128; ++k) a += p[k] * Wf1[k * 64 + lane];
  a = fmaxf(a, 0.f);
  float prod = a * Wf2[lane];
#pragma unroll
  for (int off = 32; off; off >>= 1) prod += __shfl_down(prod, off);
  if (lane == 0) out[g] = prod + bf2[0];
}

// ---------------- launch ----------------

static inline size_t align256(size_t x) { return (x + 255) & ~(size_t)255; }

extern "C" void kernel_launch(void* const* d_in, const int* in_sizes, int n_in,
                              void* d_out, int out_size, void* d_ws, size_t ws_size,
                              hipStream_t stream) {
  const float* x = (const float*)d_in[0];
  const int* ei = (const int*)d_in[1];
  const int* batch = (const int*)d_in[2];
  const float* W0 = (const float*)d_in[3];
  const float* b0 = (const float*)d_in[4];
  const float* W1 = (const float*)d_in[5];
  const float* b1 = (const float*)d_in[6];
  const float* W2 = (const float*)d_in[7];
  const float* b2 = (const float*)d_in[8];
  const float* Wf1 = (const float*)d_in[9];
  const float* bf1 = (const float*)d_in[10];
  const float* Wf2 = (const float*)d_in[11];
  const float* bf2 = (const float*)d_in[12];
  float* out = (float*)d_out;

  const int N = in_sizes[0] / 3;
  const int E = in_sizes[1] / 2;
  const int Gn = out_size;
  const int nbuk = (N + 255) >> 8;

  const int* src = ei;
  const int* dst = ei + E;

  char* ws = (char*)d_ws;
  size_t o = 0;
  int* cnt = (int*)(ws + o); o = align256(o + (size_t)N * 4);
  float* dis = (float*)(ws + o); o = align256(o + (size_t)N * 4);
  float4* x4 = (float4*)(ws + o); o = align256(o + (size_t)N * 16);
  float4* z4 = (float4*)(ws + o); o = align256(o + (size_t)N * 16);
  int* ell = (int*)(ws + o); o = align256(o + (size_t)N * ELLW * 4);
  _Float16* g16a = (_Float16*)(ws + o); o = align256(o + (size_t)N * HID * 2);
  _Float16* q1 = (_Float16*)(ws + o); o = align256(o + (size_t)N * HID * 2);
  _Float16* wt1 = (_Float16*)(ws + o); o = align256(o + (size_t)HID * HID * 2);
  _Float16* wt2 = (_Float16*)(ws + o); o = align256(o + (size_t)HID * HID * 2);
  // bkcnt(+ovfn) and pool adjacent -> single zeroing launch covers both
  size_t zero_base = o;
  int* bkcnt = (int*)(ws + o); o = align256(o + (size_t)(NBINS + 1) * 4);
  int* ovfn = bkcnt + NBINS;
  float* pool = (float*)(ws + o); o = align256(o + (size_t)Gn * HID * 4);
  size_t zero_bytes = o - zero_base;
  unsigned* bk = (unsigned*)(ws + o); o = align256(o + (size_t)NBINS * BKCAP * 4);
  int2* ovf = (int2*)(ws + o); o = align256(o + (size_t)OVF_CAP * 8);

  const int BS = 256;
  int gN = (N + BS - 1) / BS;
  int gN16 = (int)(((long long)N * 16 + BS - 1) / BS);
  int gW2 = (2 * HID * HID + BS - 1) / BS;
  int zn = (int)(zero_bytes / 4);

  // ---- zero bkcnt + ovfn + pool in one launch ----
  k_zero_ints<<<(zn + BS - 1) / BS, BS, 0, stream>>>((int*)(ws + zero_base), zn);

  // ---- ELL build ----
  bool vec4ok = (E % 4 == 0) && (((uintptr_t)src & 15) == 0) && (((uintptr_t)dst & 15) == 0);
  if (nbuk <= NBINS) {
    int E4 = E / 4;
    if (E4 > 0 && vec4ok) {
      k_binA<<<(E4 + CHUNK_I4 - 1) / CHUNK_I4, 256, 0, stream>>>(
          (const int4*)src, (const int4*)dst, E4, bkcnt, bk, ovfn, ovf);
      if (E % 4) k_tail_ovf<<<1, 64, 0, stream>>>(src, dst, E4 * 4, E, ovfn, ovf);
    } else {
      k_tail_ovf<<<1, 256, 0, stream>>>(src, dst, 0, E, ovfn, ovf);
    }
    k_ell_build2<<<nbuk, 256, 0, stream>>>(bk, bkcnt, ell, cnt, N);
    k_ovf_build<<<1, 256, 0, stream>>>(ovf, ovfn, cnt, ell);
  } else {
    k_zero_ints<<<gN, BS, 0, stream>>>(cnt, N);
    k_fill_ell1<<<(E + BS - 1) / BS, BS, 0, stream>>>(src, dst, cnt, ell, E);
  }

  // ---- dis + x4 ----
  k_dis_prepx<<<gN, BS, 0, stream>>>(cnt, x, dis, x4, N);

  // ---- weight prep ----
  k_prep_w16x2<<<gW2, BS, 0, stream>>>(W1, W2, wt1, wt2);

  // ---- layer 0 aggregate ----
  k_agg3<<<gN, BS, 0, stream>>>(x4, ell, cnt, dis, z4, N);

  // ---- fused: h0 = relu(z4@W0+b0); g16a = dis * (h0 @ W1) ----
  k_l01<<<(N + 63) / 64, 256, 0, stream>>>(z4, W0, b0, wt1, dis, g16a, N);

  // ---- pure gather: q1 = dis * relu(dis * (A g16a) + b1) ----
  k_g1<<<gN16, BS, 0, stream>>>(g16a, ell, cnt, dis, b1, q1, N);

  // ---- final: gather(q1) -> v -> @W2 + b2, relu -> pool ----
  k_gpool2<<<(N + 15) / 16, 256, 0, stream>>>(q1, ell, cnt, dis, b2, wt2, batch, pool, N);

  // ---- MLP head ----
  k_mlp512<<<Gn, 64, 0, stream>>>(pool, batch, N, Wf1, bf1, Wf2, bf2, out);
}